// Round 17
// baseline (400.811 us; speedup 1.0000x reference)
//
#include <hip/hip_runtime.h>
#include <cstddef>
#include <cstdint>

typedef __bf16 bf16;
typedef __bf16 bf16x8 __attribute__((ext_vector_type(8)));
typedef __bf16 bf16x4 __attribute__((ext_vector_type(4)));
typedef float  f32x4  __attribute__((ext_vector_type(4)));
typedef uint32_t u32x2 __attribute__((ext_vector_type(2)));
typedef uint32_t u32x4 __attribute__((ext_vector_type(4)));

#define NTOK 49
#define QK_SCALE 0.17677669529663687f   // 32^-0.5
#define LOG2E    1.4426950408889634f
#define QS       (QK_SCALE * LOG2E)     // folded into wT q-cols (prep) + q bias

// workspace byte offsets
#define WS_WT   0          // 768*256 bf16 = 393216 B
#define WS_PJT  393216     // 256*256 bf16 = 131072 B
#define WS_P    524288     // 169*8 f32 (padded to 8192)
#define WS_RPBQ 532480     // 8*64*64 f32 = 131072 B (end: 663552)

// ---------------- prep: transpose + bf16-convert weights ----------------
__global__ void prep_weights(const float* __restrict__ qkv_w, const float* __restrict__ proj_w,
                             bf16* __restrict__ wT, bf16* __restrict__ pjT) {
  int tid = blockIdx.x * 256 + threadIdx.x;
  if (tid < 768 * 256) {
    int n = tid >> 8, k = tid & 255;
    float v = qkv_w[k * 768 + n];
    if (n < 256) v *= QS;
    wT[tid] = (bf16)v;                          // wT[n][k]
  } else {
    int t = tid - 768 * 256;
    int n = t >> 8, k = t & 255;
    pjT[t] = (bf16)proj_w[k * 256 + n];         // pjT[n][k]
  }
}

// ---------------- prep: position-bias MLP (169 rows, tiny) ----------------
__device__ __forceinline__ void mlp_layer(float* p, const float* g, const float* be,
                                          const float* w, const float* bb, int nout) {
  float m = 0.f;
#pragma unroll
  for (int j = 0; j < 16; ++j) m += p[j];
  m *= (1.f / 16.f);
  float v = 0.f;
#pragma unroll
  for (int j = 0; j < 16; ++j) { float d = p[j] - m; v += d * d; }
  v *= (1.f / 16.f);
  float rs = rsqrtf(v + 1e-5f);
  float t[16];
#pragma unroll
  for (int j = 0; j < 16; ++j) {
    float u = (p[j] - m) * rs * g[j] + be[j];
    t[j] = u > 0.f ? u : 0.f;
  }
  float o[16];
  for (int j = 0; j < nout; ++j) {
    float s = bb[j];
#pragma unroll
    for (int k = 0; k < 16; ++k) s += t[k] * w[k * nout + j];
    o[j] = s;
  }
  for (int j = 0; j < nout; ++j) p[j] = o[j];
}

__global__ void pos_mlp(const float* __restrict__ biases, const float* __restrict__ ppw,
                        const float* __restrict__ ppb,
                        const float* g1, const float* be1, const float* w1, const float* bb1,
                        const float* g2, const float* be2, const float* w2, const float* bb2,
                        const float* g3, const float* be3, const float* w3, const float* bb3,
                        float* __restrict__ p_out) {
  int i = blockIdx.x * blockDim.x + threadIdx.x;
  if (i >= 169) return;
  float p[16];
  float y0 = biases[2 * i], y1 = biases[2 * i + 1];
#pragma unroll
  for (int j = 0; j < 16; ++j) p[j] = y0 * ppw[j] + y1 * ppw[16 + j] + ppb[j];
  mlp_layer(p, g1, be1, w1, bb1, 16);
  mlp_layer(p, g2, be2, w2, bb2, 16);
  mlp_layer(p, g3, be3, w3, bb3, 8);
#pragma unroll
  for (int j = 0; j < 8; ++j) p_out[i * 8 + j] = p[j];
}

// rpbQ[h][qt][kt], 8 x 64 x 64, pre-scaled by LOG2E, key-mask baked in.
// (qt-major so S^T C-init reads f32x4 contiguous in kt)
__global__ void build_rpbQ(const float* __restrict__ p, const int* __restrict__ rel_idx,
                           float* __restrict__ rpbQ) {
  int tid = blockIdx.x * 256 + threadIdx.x;
  if (tid >= 8 * 64 * 64) return;
  int h = tid >> 12, qt = (tid >> 6) & 63, kt = tid & 63;
  float v;
  if (kt >= NTOK) v = -1e30f;                      // padded key -> exp2 -> 0
  else if (qt >= NTOK) v = 0.f;                    // padded query row -> harmless
  else v = p[rel_idx[qt * NTOK + kt] * 8 + h] * LOG2E;
  rpbQ[tid] = v;
}

// ---------------- helpers ----------------
__device__ __forceinline__ u32x2 pack4(f32x4 a) {
  uint32_t h0 = (uint32_t)__builtin_bit_cast(uint16_t, (bf16)a[0]);
  uint32_t h1 = (uint32_t)__builtin_bit_cast(uint16_t, (bf16)a[1]);
  uint32_t h2 = (uint32_t)__builtin_bit_cast(uint16_t, (bf16)a[2]);
  uint32_t h3 = (uint32_t)__builtin_bit_cast(uint16_t, (bf16)a[3]);
  u32x2 r;
  r[0] = h0 | (h1 << 16);
  r[1] = h2 | (h3 << 16);
  return r;
}

// C-layout 32x16 tile pair (pk0: rows 0-15, pk1: rows 16-31; each u32x2 =
// bf16x4 over r2) -> A/B-frag of C^T: frag[lane][j] = C[8*(lane>>4)+j][lane&15].
__device__ __forceinline__ bf16x8 xpose_frag(u32x2 pk0, u32x2 pk1, int lg, int lr) {
  const int sl0 = ((lg & 1) << 5) + lr;
  const int sl1 = sl0 + 16;
  const bool hi = lg >= 2;
  uint32_t a0 = (uint32_t)__shfl((int)pk0[0], sl0, 64);
  uint32_t b0 = (uint32_t)__shfl((int)pk1[0], sl0, 64);
  uint32_t a1 = (uint32_t)__shfl((int)pk0[1], sl0, 64);
  uint32_t b1 = (uint32_t)__shfl((int)pk1[1], sl0, 64);
  uint32_t a2 = (uint32_t)__shfl((int)pk0[0], sl1, 64);
  uint32_t b2 = (uint32_t)__shfl((int)pk1[0], sl1, 64);
  uint32_t a3 = (uint32_t)__shfl((int)pk0[1], sl1, 64);
  uint32_t b3 = (uint32_t)__shfl((int)pk1[1], sl1, 64);
  u32x4 r;
  r[0] = hi ? b0 : a0; r[1] = hi ? b1 : a1;
  r[2] = hi ? b2 : a2; r[3] = hi ? b3 : a3;
  return __builtin_bit_cast(bf16x8, r);
}

// ---------------- fused per-window attention ----------------
// block = 256 threads (4 waves) = 1 window. Wave w owns heads {w, 4+w}.
// R17 = R14 exactly (the 381us best: (256,2) cap, split q/k passes, acc
// peak 32, unroll-2, per-nq fused softmax/PV, direct ao_lds PV writes,
// original predicated-scalar-store proj - R15/R16's proj-swap regressed)
// + T5 s_setprio(1)/(0) wrapped around each MFMA cluster. Mechanism: waves
// run independent heads with no barriers in the head loop, so co-resident
// waves sit at different phases; setprio lets the CU scheduler favor the
// MFMA-issuing wave (m191: +4-7% on attn; null only under barrier-lockstep).
__launch_bounds__(256, 2)
__global__ void attn_fused(const float* __restrict__ x, const bf16* __restrict__ wT,
                           const float* __restrict__ qkv_b, const bf16* __restrict__ pjT,
                           const float* __restrict__ proj_b, const float* __restrict__ rpbQ,
                           float* __restrict__ out) {
  __shared__ __align__(16) bf16 x_lds[64 * 256];   // byte ^= (row&7)<<4
  __shared__ __align__(16) bf16 ao_lds[64 * 256];  // attn-out tile, same swizzle

  const int b = blockIdx.x;
  const int tid = threadIdx.x;
  const int w = tid >> 6;
  const int lane = tid & 63;
  const int lg = lane >> 4;
  const int lr = lane & 15;

  char* const xbase = (char*)x_lds;
  char* const abase = (char*)ao_lds;

  // ---- stage x -> bf16 LDS (swizzled), rows >= 49 zeroed ----
  const float* xb = x + (size_t)b * (NTOK * 256);
#pragma unroll
  for (int it = 0; it < 16; ++it) {
    int r = it * 4 + w;
    float4 v = make_float4(0.f, 0.f, 0.f, 0.f);
    if (r < NTOK) v = *(const float4*)(xb + r * 256 + 4 * lane);
    bf16x4 pk;
    pk[0] = (bf16)v.x; pk[1] = (bf16)v.y; pk[2] = (bf16)v.z; pk[3] = (bf16)v.w;
    *(bf16x4*)(xbase + r * 512 + ((8 * lane) ^ ((r & 7) << 4))) = pk;
  }
  __syncthreads();

  const f32x4 zero4 = {0.f, 0.f, 0.f, 0.f};

#pragma unroll
  for (int hi = 0; hi < 2; ++hi) {
    const int h = hi * 4 + w;

    const bf16* wq0 = wT + (size_t)(h * 32 + lr) * 256 + 8 * lg;
    const bf16* wq1 = wq0 + 16 * 256;
    const bf16* wk0 = wq0 + 256 * 256;
    const bf16* wk1 = wk0 + 16 * 256;
    const bf16* wv0 = wk0 + 256 * 256;
    const bf16* wv1 = wv0 + 16 * 256;

    f32x4 acc_[2][4];   // reused by q-pass then k-pass (acc peak 32)
    bf16x8 aqf[4], bkf[4];

    // ---- q pass: qT GEMM over K=256 (C rows = dims, cols = tokens) ----
#pragma unroll
    for (int mt = 0; mt < 2; ++mt)
#pragma unroll
      for (int nt = 0; nt < 4; ++nt) acc_[mt][nt] = zero4;
#pragma unroll 2
    for (int kk = 0; kk < 8; ++kk) {
      bf16x8 xf[4];
#pragma unroll
      for (int nt = 0; nt < 4; ++nt)
        xf[nt] = *(const bf16x8*)(xbase + (nt * 16 + lr) * 512 +
                                  ((64 * kk + 16 * lg) ^ ((lr & 7) << 4)));
      bf16x8 q0f = *(const bf16x8*)&wq0[kk * 32];
      bf16x8 q1f = *(const bf16x8*)&wq1[kk * 32];
      __builtin_amdgcn_s_setprio(1);
#pragma unroll
      for (int nt = 0; nt < 4; ++nt) {
        acc_[0][nt] = __builtin_amdgcn_mfma_f32_16x16x32_bf16(q0f, xf[nt], acc_[0][nt], 0, 0, 0);
        acc_[1][nt] = __builtin_amdgcn_mfma_f32_16x16x32_bf16(q1f, xf[nt], acc_[1][nt], 0, 0, 0);
      }
      __builtin_amdgcn_s_setprio(0);
    }
    {
      f32x4 qb0 = *(const f32x4*)&qkv_b[h * 32 + 4 * lg];
      f32x4 qb1 = *(const f32x4*)&qkv_b[h * 32 + 16 + 4 * lg];
#pragma unroll
      for (int t = 0; t < 4; ++t) {
        f32x4 tq0, tq1;
#pragma unroll
        for (int r2 = 0; r2 < 4; ++r2) {
          tq0[r2] = acc_[0][t][r2] + qb0[r2] * QS;
          tq1[r2] = acc_[1][t][r2] + qb1[r2] * QS;
        }
        aqf[t] = xpose_frag(pack4(tq0), pack4(tq1), lg, lr);
      }
    }

    // ---- k pass: kT GEMM (same acc array) ----
#pragma unroll
    for (int mt = 0; mt < 2; ++mt)
#pragma unroll
      for (int nt = 0; nt < 4; ++nt) acc_[mt][nt] = zero4;
#pragma unroll 2
    for (int kk = 0; kk < 8; ++kk) {
      bf16x8 xf[4];
#pragma unroll
      for (int nt = 0; nt < 4; ++nt)
        xf[nt] = *(const bf16x8*)(xbase + (nt * 16 + lr) * 512 +
                                  ((64 * kk + 16 * lg) ^ ((lr & 7) << 4)));
      bf16x8 k0f = *(const bf16x8*)&wk0[kk * 32];
      bf16x8 k1f = *(const bf16x8*)&wk1[kk * 32];
      __builtin_amdgcn_s_setprio(1);
#pragma unroll
      for (int nt = 0; nt < 4; ++nt) {
        acc_[0][nt] = __builtin_amdgcn_mfma_f32_16x16x32_bf16(k0f, xf[nt], acc_[0][nt], 0, 0, 0);
        acc_[1][nt] = __builtin_amdgcn_mfma_f32_16x16x32_bf16(k1f, xf[nt], acc_[1][nt], 0, 0, 0);
      }
      __builtin_amdgcn_s_setprio(0);
    }
    {
      f32x4 kb0 = *(const f32x4*)&qkv_b[256 + h * 32 + 4 * lg];
      f32x4 kb1 = *(const f32x4*)&qkv_b[256 + h * 32 + 16 + 4 * lg];
#pragma unroll
      for (int t = 0; t < 4; ++t) {
        f32x4 tk0, tk1;
#pragma unroll
        for (int r2 = 0; r2 < 4; ++r2) {
          tk0[r2] = acc_[0][t][r2] + kb0[r2];
          tk1[r2] = acc_[1][t][r2] + kb1[r2];
        }
        bkf[t] = xpose_frag(pack4(tk0), pack4(tk1), lg, lr);
      }
    }

    // ---- v pass: v GEMM (C rows = tokens, cols = vdims) ----
    f32x4 av_[4][2];
#pragma unroll
    for (int m = 0; m < 4; ++m) { av_[m][0] = zero4; av_[m][1] = zero4; }
#pragma unroll 2
    for (int kk = 0; kk < 8; ++kk) {
      bf16x8 xf[4];
#pragma unroll
      for (int m = 0; m < 4; ++m)
        xf[m] = *(const bf16x8*)(xbase + (m * 16 + lr) * 512 +
                                 ((64 * kk + 16 * lg) ^ ((lr & 7) << 4)));
      bf16x8 v0f = *(const bf16x8*)&wv0[kk * 32];
      bf16x8 v1f = *(const bf16x8*)&wv1[kk * 32];
      __builtin_amdgcn_s_setprio(1);
#pragma unroll
      for (int m = 0; m < 4; ++m) {
        av_[m][0] = __builtin_amdgcn_mfma_f32_16x16x32_bf16(xf[m], v0f, av_[m][0], 0, 0, 0);
        av_[m][1] = __builtin_amdgcn_mfma_f32_16x16x32_bf16(xf[m], v1f, av_[m][1], 0, 0, 0);
      }
      __builtin_amdgcn_s_setprio(0);
    }
    // v bias (cols = vdims -> uniform over r2), pack, transpose
    bf16x8 vf0[2], vf1[2];
    {
      const float vbA = qkv_b[512 + h * 32 + lr];
      const float vbB = qkv_b[512 + h * 32 + 16 + lr];
#pragma unroll
      for (int nv = 0; nv < 2; ++nv) {
        const float vb = nv ? vbB : vbA;
        f32x4 t0, t1, t2, t3;
#pragma unroll
        for (int r2 = 0; r2 < 4; ++r2) {
          t0[r2] = av_[0][nv][r2] + vb;
          t1[r2] = av_[1][nv][r2] + vb;
          t2[r2] = av_[2][nv][r2] + vb;
          t3[r2] = av_[3][nv][r2] + vb;
        }
        vf0[nv] = xpose_frag(pack4(t0), pack4(t1), lg, lr);
        vf1[nv] = xpose_frag(pack4(t2), pack4(t3), lg, lr);
      }
    }

    // ---- per-nq: QK^T column -> softmax -> PV -> direct ao_lds write ----
    // Sc[mk] C element (lane,r2) = S^T[key = mk*16+4lg+r2][q = nq*16+lr]
    const float* rpbh = rpbQ + h * 4096;
#pragma unroll
    for (int nq = 0; nq < 4; ++nq) {
      f32x4 Sc[4];
      {
        f32x4 rv0 = *(const f32x4*)&rpbh[(nq * 16 + lr) * 64 + 4 * lg];
        f32x4 rv1 = *(const f32x4*)&rpbh[(nq * 16 + lr) * 64 + 16 + 4 * lg];
        f32x4 rv2 = *(const f32x4*)&rpbh[(nq * 16 + lr) * 64 + 32 + 4 * lg];
        f32x4 rv3 = *(const f32x4*)&rpbh[(nq * 16 + lr) * 64 + 48 + 4 * lg];
        __builtin_amdgcn_s_setprio(1);
        Sc[0] = __builtin_amdgcn_mfma_f32_16x16x32_bf16(bkf[0], aqf[nq], rv0, 0, 0, 0);
        Sc[1] = __builtin_amdgcn_mfma_f32_16x16x32_bf16(bkf[1], aqf[nq], rv1, 0, 0, 0);
        Sc[2] = __builtin_amdgcn_mfma_f32_16x16x32_bf16(bkf[2], aqf[nq], rv2, 0, 0, 0);
        Sc[3] = __builtin_amdgcn_mfma_f32_16x16x32_bf16(bkf[3], aqf[nq], rv3, 0, 0, 0);
        __builtin_amdgcn_s_setprio(0);
      }
      // softmax (base-2) over this q-column: 16 in-reg + shfl over lg axis
      float mx = -3.0e38f;
#pragma unroll
      for (int mk = 0; mk < 4; ++mk)
#pragma unroll
        for (int r2 = 0; r2 < 4; ++r2) mx = fmaxf(mx, Sc[mk][r2]);
      mx = fmaxf(mx, __shfl_xor(mx, 16, 64));
      mx = fmaxf(mx, __shfl_xor(mx, 32, 64));
      float sum = 0.f;
#pragma unroll
      for (int mk = 0; mk < 4; ++mk)
#pragma unroll
        for (int r2 = 0; r2 < 4; ++r2) {
          float e = exp2f(Sc[mk][r2] - mx);
          Sc[mk][r2] = e;
          sum += e;
        }
      sum += __shfl_xor(sum, 16, 64);
      sum += __shfl_xor(sum, 32, 64);
      const float inv = 1.f / sum;
#pragma unroll
      for (int mk = 0; mk < 4; ++mk)
#pragma unroll
        for (int r2 = 0; r2 < 4; ++r2) Sc[mk][r2] *= inv;

      // pack + transpose -> PV A-frags for this q-row block (local, 8 regs)
      bf16x8 pa0 = xpose_frag(pack4(Sc[0]), pack4(Sc[1]), lg, lr);  // keys 0-31
      bf16x8 pa1 = xpose_frag(pack4(Sc[2]), pack4(Sc[3]), lg, lr);  // keys 32-63

      // PV for rows nq*16..+15: o = P @ V, write straight to ao_lds
#pragma unroll
      for (int nv = 0; nv < 2; ++nv) {
        __builtin_amdgcn_s_setprio(1);
        f32x4 o = __builtin_amdgcn_mfma_f32_16x16x32_bf16(pa0, vf0[nv], zero4, 0, 0, 0);
        o = __builtin_amdgcn_mfma_f32_16x16x32_bf16(pa1, vf1[nv], o, 0, 0, 0);
        __builtin_amdgcn_s_setprio(0);
        bf16x4 pk = __builtin_bit_cast(bf16x4, pack4(o));
#pragma unroll
        for (int r2 = 0; r2 < 4; ++r2) {
          const int r = nq * 16 + 4 * lg + r2;
          *(bf16*)(abase + r * 512 +
                   ((2 * (h * 32 + nv * 16 + lr)) ^ ((r & 7) << 4))) = pk[r2];
        }
      }
    }
  }

  __syncthreads();  // all ao writes visible

  // ---- proj: out = ao(64x256) @ proj_w + b; wave w owns 64 output cols ----
  f32x4 c2[4][4];
  const bf16* pjrow[4];
#pragma unroll
  for (int n = 0; n < 4; ++n) {
    const int col = w * 64 + n * 16 + lr;
    const float pb = proj_b[col];
#pragma unroll
    for (int m = 0; m < 4; ++m) {
      c2[m][n][0] = pb; c2[m][n][1] = pb; c2[m][n][2] = pb; c2[m][n][3] = pb;
    }
    pjrow[n] = pjT + (size_t)col * 256 + 8 * lg;
  }
#pragma unroll 2
  for (int kk = 0; kk < 8; ++kk) {
    bf16x8 afr[4];
#pragma unroll
    for (int m = 0; m < 4; ++m)
      afr[m] = *(const bf16x8*)(abase + (m * 16 + lr) * 512 +
                                ((64 * kk + 16 * lg) ^ ((lr & 7) << 4)));
#pragma unroll
    for (int n = 0; n < 4; ++n) {
      bf16x8 bfr = *(const bf16x8*)&pjrow[n][kk * 32];
      __builtin_amdgcn_s_setprio(1);
#pragma unroll
      for (int m = 0; m < 4; ++m)
        c2[m][n] = __builtin_amdgcn_mfma_f32_16x16x32_bf16(afr[m], bfr, c2[m][n], 0, 0, 0);
      __builtin_amdgcn_s_setprio(0);
    }
  }
  float* ob = out + (size_t)b * (NTOK * 256);
#pragma unroll
  for (int n = 0; n < 4; ++n) {
    const int col = w * 64 + n * 16 + lr;
#pragma unroll
    for (int m = 0; m < 4; ++m)
#pragma unroll
      for (int r2 = 0; r2 < 4; ++r2) {
        const int row = m * 16 + lg * 4 + r2;
        if (row < NTOK) ob[row * 256 + col] = c2[m][n][r2];
      }
  }
}

// ---------------- launcher ----------------
extern "C" void kernel_launch(void* const* d_in, const int* in_sizes, int n_in,
                              void* d_out, int out_size, void* d_ws, size_t ws_size,
                              hipStream_t stream) {
  (void)in_sizes; (void)n_in; (void)out_size; (void)ws_size;
  const float* x      = (const float*)d_in[0];
  const float* qkv_w  = (const float*)d_in[1];
  const float* qkv_b  = (const float*)d_in[2];
  const float* proj_w = (const float*)d_in[3];
  const float* proj_b = (const float*)d_in[4];
  const float* ppw    = (const float*)d_in[5];
  const float* ppb    = (const float*)d_in[6];
  const float* ln1_g  = (const float*)d_in[7];
  const float* ln1_b  = (const float*)d_in[8];
  const float* w1     = (const float*)d_in[9];
  const float* b1     = (const float*)d_in[10];
  const float* ln2_g  = (const float*)d_in[11];
  const float* ln2_b  = (const float*)d_in[12];
  const float* w2     = (const float*)d_in[13];
  const float* b2     = (const float*)d_in[14];
  const float* ln3_g  = (const float*)d_in[15];
  const float* ln3_b  = (const float*)d_in[16];
  const float* w3     = (const float*)d_in[17];
  const float* b3     = (const float*)d_in[18];
  const float* biases = (const float*)d_in[19];
  const int*   relidx = (const int*)d_in[20];

  char* ws = (char*)d_ws;
  bf16*  wT   = (bf16*)(ws + WS_WT);
  bf16*  pjT  = (bf16*)(ws + WS_PJT);
  float* p_ws = (float*)(ws + WS_P);
  float* rpbQ = (float*)(ws + WS_RPBQ);

  prep_weights<<<1024, 256, 0, stream>>>(qkv_w, proj_w, wT, pjT);
  pos_mlp<<<1, 256, 0, stream>>>(biases, ppw, ppb,
                                 ln1_g, ln1_b, w1, b1,
                                 ln2_g, ln2_b, w2, b2,
                                 ln3_g, ln3_b, w3, b3, p_ws);
  build_rpbQ<<<128, 256, 0, stream>>>(p_ws, relidx, rpbQ);
  attn_fused<<<4096, 256, 0, stream>>>(x, wT, qkv_b, pjT, proj_b, rpbQ, (float*)d_out);
}

// Round 18
// 382.560 us; speedup vs baseline: 1.0477x; 1.0477x over previous
//
#include <hip/hip_runtime.h>
#include <cstddef>
#include <cstdint>

typedef __bf16 bf16;
typedef __bf16 bf16x8 __attribute__((ext_vector_type(8)));
typedef __bf16 bf16x4 __attribute__((ext_vector_type(4)));
typedef float  f32x4  __attribute__((ext_vector_type(4)));
typedef uint32_t u32x2 __attribute__((ext_vector_type(2)));
typedef uint32_t u32x4 __attribute__((ext_vector_type(4)));

#define NTOK 49
#define QK_SCALE 0.17677669529663687f   // 32^-0.5
#define LOG2E    1.4426950408889634f
#define QS       (QK_SCALE * LOG2E)     // folded into wT q-cols (prep) + q bias

// workspace byte offsets
#define WS_WT   0          // 768*256 bf16 = 393216 B
#define WS_PJT  393216     // 256*256 bf16 = 131072 B
#define WS_P    524288     // 169*8 f32 (padded to 8192)
#define WS_RPBQ 532480     // 8*64*64 f32 = 131072 B (end: 663552)

// ---------------- prep: transpose + bf16-convert weights ----------------
__global__ void prep_weights(const float* __restrict__ qkv_w, const float* __restrict__ proj_w,
                             bf16* __restrict__ wT, bf16* __restrict__ pjT) {
  int tid = blockIdx.x * 256 + threadIdx.x;
  if (tid < 768 * 256) {
    int n = tid >> 8, k = tid & 255;
    float v = qkv_w[k * 768 + n];
    if (n < 256) v *= QS;
    wT[tid] = (bf16)v;                          // wT[n][k]
  } else {
    int t = tid - 768 * 256;
    int n = t >> 8, k = t & 255;
    pjT[t] = (bf16)proj_w[k * 256 + n];         // pjT[n][k]
  }
}

// ---------------- prep: position-bias MLP (169 rows, tiny) ----------------
__device__ __forceinline__ void mlp_layer(float* p, const float* g, const float* be,
                                          const float* w, const float* bb, int nout) {
  float m = 0.f;
#pragma unroll
  for (int j = 0; j < 16; ++j) m += p[j];
  m *= (1.f / 16.f);
  float v = 0.f;
#pragma unroll
  for (int j = 0; j < 16; ++j) { float d = p[j] - m; v += d * d; }
  v *= (1.f / 16.f);
  float rs = rsqrtf(v + 1e-5f);
  float t[16];
#pragma unroll
  for (int j = 0; j < 16; ++j) {
    float u = (p[j] - m) * rs * g[j] + be[j];
    t[j] = u > 0.f ? u : 0.f;
  }
  float o[16];
  for (int j = 0; j < nout; ++j) {
    float s = bb[j];
#pragma unroll
    for (int k = 0; k < 16; ++k) s += t[k] * w[k * nout + j];
    o[j] = s;
  }
  for (int j = 0; j < nout; ++j) p[j] = o[j];
}

__global__ void pos_mlp(const float* __restrict__ biases, const float* __restrict__ ppw,
                        const float* __restrict__ ppb,
                        const float* g1, const float* be1, const float* w1, const float* bb1,
                        const float* g2, const float* be2, const float* w2, const float* bb2,
                        const float* g3, const float* be3, const float* w3, const float* bb3,
                        float* __restrict__ p_out) {
  int i = blockIdx.x * blockDim.x + threadIdx.x;
  if (i >= 169) return;
  float p[16];
  float y0 = biases[2 * i], y1 = biases[2 * i + 1];
#pragma unroll
  for (int j = 0; j < 16; ++j) p[j] = y0 * ppw[j] + y1 * ppw[16 + j] + ppb[j];
  mlp_layer(p, g1, be1, w1, bb1, 16);
  mlp_layer(p, g2, be2, w2, bb2, 16);
  mlp_layer(p, g3, be3, w3, bb3, 8);
#pragma unroll
  for (int j = 0; j < 8; ++j) p_out[i * 8 + j] = p[j];
}

// rpbQ[h][qt][kt], 8 x 64 x 64, pre-scaled by LOG2E, key-mask baked in.
// (qt-major so S^T C-init reads f32x4 contiguous in kt)
__global__ void build_rpbQ(const float* __restrict__ p, const int* __restrict__ rel_idx,
                           float* __restrict__ rpbQ) {
  int tid = blockIdx.x * 256 + threadIdx.x;
  if (tid >= 8 * 64 * 64) return;
  int h = tid >> 12, qt = (tid >> 6) & 63, kt = tid & 63;
  float v;
  if (kt >= NTOK) v = -1e30f;                      // padded key -> exp2 -> 0
  else if (qt >= NTOK) v = 0.f;                    // padded query row -> harmless
  else v = p[rel_idx[qt * NTOK + kt] * 8 + h] * LOG2E;
  rpbQ[tid] = v;
}

// ---------------- helpers ----------------
__device__ __forceinline__ u32x2 pack4(f32x4 a) {
  uint32_t h0 = (uint32_t)__builtin_bit_cast(uint16_t, (bf16)a[0]);
  uint32_t h1 = (uint32_t)__builtin_bit_cast(uint16_t, (bf16)a[1]);
  uint32_t h2 = (uint32_t)__builtin_bit_cast(uint16_t, (bf16)a[2]);
  uint32_t h3 = (uint32_t)__builtin_bit_cast(uint16_t, (bf16)a[3]);
  u32x2 r;
  r[0] = h0 | (h1 << 16);
  r[1] = h2 | (h3 << 16);
  return r;
}

// C-layout 32x16 tile pair (pk0: rows 0-15, pk1: rows 16-31; each u32x2 =
// bf16x4 over r2) -> A/B-frag of C^T: frag[lane][j] = C[8*(lane>>4)+j][lane&15].
__device__ __forceinline__ bf16x8 xpose_frag(u32x2 pk0, u32x2 pk1, int lg, int lr) {
  const int sl0 = ((lg & 1) << 5) + lr;
  const int sl1 = sl0 + 16;
  const bool hi = lg >= 2;
  uint32_t a0 = (uint32_t)__shfl((int)pk0[0], sl0, 64);
  uint32_t b0 = (uint32_t)__shfl((int)pk1[0], sl0, 64);
  uint32_t a1 = (uint32_t)__shfl((int)pk0[1], sl0, 64);
  uint32_t b1 = (uint32_t)__shfl((int)pk1[1], sl0, 64);
  uint32_t a2 = (uint32_t)__shfl((int)pk0[0], sl1, 64);
  uint32_t b2 = (uint32_t)__shfl((int)pk1[0], sl1, 64);
  uint32_t a3 = (uint32_t)__shfl((int)pk0[1], sl1, 64);
  uint32_t b3 = (uint32_t)__shfl((int)pk1[1], sl1, 64);
  u32x4 r;
  r[0] = hi ? b0 : a0; r[1] = hi ? b1 : a1;
  r[2] = hi ? b2 : a2; r[3] = hi ? b3 : a3;
  return __builtin_bit_cast(bf16x8, r);
}

// ---------------- fused per-window attention ----------------
// block = 256 threads (4 waves) = 1 window. Wave w owns heads {w, 4+w}.
// R18 = R14 (the 381us best: (256,2) cap, split q/k passes, acc peak 32,
// unroll-2, direct ao_lds PV writes, predicated-scalar-store proj) with
// ONE change: nq-PAIRING in the attention tail (Sc[2][4], +16 arch regs
// ~112 <= 128 cap). Clean test of the pairing mechanism - R16 bundled it
// with the proj-swap, which R15 independently measured as ~-8us. Two
// independent softmax chains per phase hide exp2 + shfl latency; 8
// back-to-back QK MFMAs and 4 back-to-back PV MFMAs per pair.
__launch_bounds__(256, 2)
__global__ void attn_fused(const float* __restrict__ x, const bf16* __restrict__ wT,
                           const float* __restrict__ qkv_b, const bf16* __restrict__ pjT,
                           const float* __restrict__ proj_b, const float* __restrict__ rpbQ,
                           float* __restrict__ out) {
  __shared__ __align__(16) bf16 x_lds[64 * 256];   // byte ^= (row&7)<<4
  __shared__ __align__(16) bf16 ao_lds[64 * 256];  // attn-out tile, same swizzle

  const int b = blockIdx.x;
  const int tid = threadIdx.x;
  const int w = tid >> 6;
  const int lane = tid & 63;
  const int lg = lane >> 4;
  const int lr = lane & 15;

  char* const xbase = (char*)x_lds;
  char* const abase = (char*)ao_lds;

  // ---- stage x -> bf16 LDS (swizzled), rows >= 49 zeroed ----
  const float* xb = x + (size_t)b * (NTOK * 256);
#pragma unroll
  for (int it = 0; it < 16; ++it) {
    int r = it * 4 + w;
    float4 v = make_float4(0.f, 0.f, 0.f, 0.f);
    if (r < NTOK) v = *(const float4*)(xb + r * 256 + 4 * lane);
    bf16x4 pk;
    pk[0] = (bf16)v.x; pk[1] = (bf16)v.y; pk[2] = (bf16)v.z; pk[3] = (bf16)v.w;
    *(bf16x4*)(xbase + r * 512 + ((8 * lane) ^ ((r & 7) << 4))) = pk;
  }
  __syncthreads();

  const f32x4 zero4 = {0.f, 0.f, 0.f, 0.f};

#pragma unroll
  for (int hi = 0; hi < 2; ++hi) {
    const int h = hi * 4 + w;

    const bf16* wq0 = wT + (size_t)(h * 32 + lr) * 256 + 8 * lg;
    const bf16* wq1 = wq0 + 16 * 256;
    const bf16* wk0 = wq0 + 256 * 256;
    const bf16* wk1 = wk0 + 16 * 256;
    const bf16* wv0 = wk0 + 256 * 256;
    const bf16* wv1 = wv0 + 16 * 256;

    f32x4 acc_[2][4];   // reused by q-pass then k-pass (acc peak 32)
    bf16x8 aqf[4], bkf[4];

    // ---- q pass: qT GEMM over K=256 (C rows = dims, cols = tokens) ----
#pragma unroll
    for (int mt = 0; mt < 2; ++mt)
#pragma unroll
      for (int nt = 0; nt < 4; ++nt) acc_[mt][nt] = zero4;
#pragma unroll 2
    for (int kk = 0; kk < 8; ++kk) {
      bf16x8 xf[4];
#pragma unroll
      for (int nt = 0; nt < 4; ++nt)
        xf[nt] = *(const bf16x8*)(xbase + (nt * 16 + lr) * 512 +
                                  ((64 * kk + 16 * lg) ^ ((lr & 7) << 4)));
      bf16x8 q0f = *(const bf16x8*)&wq0[kk * 32];
      bf16x8 q1f = *(const bf16x8*)&wq1[kk * 32];
#pragma unroll
      for (int nt = 0; nt < 4; ++nt) {
        acc_[0][nt] = __builtin_amdgcn_mfma_f32_16x16x32_bf16(q0f, xf[nt], acc_[0][nt], 0, 0, 0);
        acc_[1][nt] = __builtin_amdgcn_mfma_f32_16x16x32_bf16(q1f, xf[nt], acc_[1][nt], 0, 0, 0);
      }
    }
    {
      f32x4 qb0 = *(const f32x4*)&qkv_b[h * 32 + 4 * lg];
      f32x4 qb1 = *(const f32x4*)&qkv_b[h * 32 + 16 + 4 * lg];
#pragma unroll
      for (int t = 0; t < 4; ++t) {
        f32x4 tq0, tq1;
#pragma unroll
        for (int r2 = 0; r2 < 4; ++r2) {
          tq0[r2] = acc_[0][t][r2] + qb0[r2] * QS;
          tq1[r2] = acc_[1][t][r2] + qb1[r2] * QS;
        }
        aqf[t] = xpose_frag(pack4(tq0), pack4(tq1), lg, lr);
      }
    }

    // ---- k pass: kT GEMM (same acc array) ----
#pragma unroll
    for (int mt = 0; mt < 2; ++mt)
#pragma unroll
      for (int nt = 0; nt < 4; ++nt) acc_[mt][nt] = zero4;
#pragma unroll 2
    for (int kk = 0; kk < 8; ++kk) {
      bf16x8 xf[4];
#pragma unroll
      for (int nt = 0; nt < 4; ++nt)
        xf[nt] = *(const bf16x8*)(xbase + (nt * 16 + lr) * 512 +
                                  ((64 * kk + 16 * lg) ^ ((lr & 7) << 4)));
      bf16x8 k0f = *(const bf16x8*)&wk0[kk * 32];
      bf16x8 k1f = *(const bf16x8*)&wk1[kk * 32];
#pragma unroll
      for (int nt = 0; nt < 4; ++nt) {
        acc_[0][nt] = __builtin_amdgcn_mfma_f32_16x16x32_bf16(k0f, xf[nt], acc_[0][nt], 0, 0, 0);
        acc_[1][nt] = __builtin_amdgcn_mfma_f32_16x16x32_bf16(k1f, xf[nt], acc_[1][nt], 0, 0, 0);
      }
    }
    {
      f32x4 kb0 = *(const f32x4*)&qkv_b[256 + h * 32 + 4 * lg];
      f32x4 kb1 = *(const f32x4*)&qkv_b[256 + h * 32 + 16 + 4 * lg];
#pragma unroll
      for (int t = 0; t < 4; ++t) {
        f32x4 tk0, tk1;
#pragma unroll
        for (int r2 = 0; r2 < 4; ++r2) {
          tk0[r2] = acc_[0][t][r2] + kb0[r2];
          tk1[r2] = acc_[1][t][r2] + kb1[r2];
        }
        bkf[t] = xpose_frag(pack4(tk0), pack4(tk1), lg, lr);
      }
    }

    // ---- v pass: v GEMM (C rows = tokens, cols = vdims) ----
    f32x4 av_[4][2];
#pragma unroll
    for (int m = 0; m < 4; ++m) { av_[m][0] = zero4; av_[m][1] = zero4; }
#pragma unroll 2
    for (int kk = 0; kk < 8; ++kk) {
      bf16x8 xf[4];
#pragma unroll
      for (int m = 0; m < 4; ++m)
        xf[m] = *(const bf16x8*)(xbase + (m * 16 + lr) * 512 +
                                 ((64 * kk + 16 * lg) ^ ((lr & 7) << 4)));
      bf16x8 v0f = *(const bf16x8*)&wv0[kk * 32];
      bf16x8 v1f = *(const bf16x8*)&wv1[kk * 32];
#pragma unroll
      for (int m = 0; m < 4; ++m) {
        av_[m][0] = __builtin_amdgcn_mfma_f32_16x16x32_bf16(xf[m], v0f, av_[m][0], 0, 0, 0);
        av_[m][1] = __builtin_amdgcn_mfma_f32_16x16x32_bf16(xf[m], v1f, av_[m][1], 0, 0, 0);
      }
    }
    // v bias (cols = vdims -> uniform over r2), pack, transpose
    bf16x8 vf0[2], vf1[2];
    {
      const float vbA = qkv_b[512 + h * 32 + lr];
      const float vbB = qkv_b[512 + h * 32 + 16 + lr];
#pragma unroll
      for (int nv = 0; nv < 2; ++nv) {
        const float vb = nv ? vbB : vbA;
        f32x4 t0, t1, t2, t3;
#pragma unroll
        for (int r2 = 0; r2 < 4; ++r2) {
          t0[r2] = av_[0][nv][r2] + vb;
          t1[r2] = av_[1][nv][r2] + vb;
          t2[r2] = av_[2][nv][r2] + vb;
          t3[r2] = av_[3][nv][r2] + vb;
        }
        vf0[nv] = xpose_frag(pack4(t0), pack4(t1), lg, lr);
        vf1[nv] = xpose_frag(pack4(t2), pack4(t3), lg, lr);
      }
    }

    // ---- paired per-nq: 2x{QK col -> softmax -> PV -> ao_lds write} ----
    // Sc[q2][mk] C element (lane,r2) = S^T[key mk*16+4lg+r2][q nq*16+lr]
    const float* rpbh = rpbQ + h * 4096;
#pragma unroll
    for (int np = 0; np < 2; ++np) {
      f32x4 Sc[2][4];
#pragma unroll
      for (int q2 = 0; q2 < 2; ++q2) {
        const int nq = np * 2 + q2;
#pragma unroll
        for (int mk = 0; mk < 4; ++mk) {
          f32x4 rv = *(const f32x4*)&rpbh[(nq * 16 + lr) * 64 + mk * 16 + 4 * lg];
          Sc[q2][mk] = __builtin_amdgcn_mfma_f32_16x16x32_bf16(bkf[mk], aqf[nq], rv, 0, 0, 0);
        }
      }
      // two independent softmax chains (base-2)
#pragma unroll
      for (int q2 = 0; q2 < 2; ++q2) {
        float mx = -3.0e38f;
#pragma unroll
        for (int mk = 0; mk < 4; ++mk)
#pragma unroll
          for (int r2 = 0; r2 < 4; ++r2) mx = fmaxf(mx, Sc[q2][mk][r2]);
        mx = fmaxf(mx, __shfl_xor(mx, 16, 64));
        mx = fmaxf(mx, __shfl_xor(mx, 32, 64));
        float sum = 0.f;
#pragma unroll
        for (int mk = 0; mk < 4; ++mk)
#pragma unroll
          for (int r2 = 0; r2 < 4; ++r2) {
            float e = exp2f(Sc[q2][mk][r2] - mx);
            Sc[q2][mk][r2] = e;
            sum += e;
          }
        sum += __shfl_xor(sum, 16, 64);
        sum += __shfl_xor(sum, 32, 64);
        const float inv = 1.f / sum;
#pragma unroll
        for (int mk = 0; mk < 4; ++mk)
#pragma unroll
          for (int r2 = 0; r2 < 4; ++r2) Sc[q2][mk][r2] *= inv;
      }
      // pack + transpose + PV + direct ao write, per column group
#pragma unroll
      for (int q2 = 0; q2 < 2; ++q2) {
        const int nq = np * 2 + q2;
        bf16x8 pa0 = xpose_frag(pack4(Sc[q2][0]), pack4(Sc[q2][1]), lg, lr);
        bf16x8 pa1 = xpose_frag(pack4(Sc[q2][2]), pack4(Sc[q2][3]), lg, lr);
#pragma unroll
        for (int nv = 0; nv < 2; ++nv) {
          f32x4 o = __builtin_amdgcn_mfma_f32_16x16x32_bf16(pa0, vf0[nv], zero4, 0, 0, 0);
          o = __builtin_amdgcn_mfma_f32_16x16x32_bf16(pa1, vf1[nv], o, 0, 0, 0);
          bf16x4 pk = __builtin_bit_cast(bf16x4, pack4(o));
#pragma unroll
          for (int r2 = 0; r2 < 4; ++r2) {
            const int r = nq * 16 + 4 * lg + r2;
            *(bf16*)(abase + r * 512 +
                     ((2 * (h * 32 + nv * 16 + lr)) ^ ((r & 7) << 4))) = pk[r2];
          }
        }
      }
    }
  }

  __syncthreads();  // all ao writes visible

  // ---- proj: out = ao(64x256) @ proj_w + b; wave w owns 64 output cols ----
  f32x4 c2[4][4];
  const bf16* pjrow[4];
#pragma unroll
  for (int n = 0; n < 4; ++n) {
    const int col = w * 64 + n * 16 + lr;
    const float pb = proj_b[col];
#pragma unroll
    for (int m = 0; m < 4; ++m) {
      c2[m][n][0] = pb; c2[m][n][1] = pb; c2[m][n][2] = pb; c2[m][n][3] = pb;
    }
    pjrow[n] = pjT + (size_t)col * 256 + 8 * lg;
  }
#pragma unroll 2
  for (int kk = 0; kk < 8; ++kk) {
    bf16x8 afr[4];
#pragma unroll
    for (int m = 0; m < 4; ++m)
      afr[m] = *(const bf16x8*)(abase + (m * 16 + lr) * 512 +
                                ((64 * kk + 16 * lg) ^ ((lr & 7) << 4)));
#pragma unroll
    for (int n = 0; n < 4; ++n) {
      bf16x8 bfr = *(const bf16x8*)&pjrow[n][kk * 32];
#pragma unroll
      for (int m = 0; m < 4; ++m)
        c2[m][n] = __builtin_amdgcn_mfma_f32_16x16x32_bf16(afr[m], bfr, c2[m][n], 0, 0, 0);
    }
  }
  float* ob = out + (size_t)b * (NTOK * 256);
#pragma unroll
  for (int n = 0; n < 4; ++n) {
    const int col = w * 64 + n * 16 + lr;
#pragma unroll
    for (int m = 0; m < 4; ++m)
#pragma unroll
      for (int r2 = 0; r2 < 4; ++r2) {
        const int row = m * 16 + lg * 4 + r2;
        if (row < NTOK) ob[row * 256 + col] = c2[m][n][r2];
      }
  }
}

// ---------------- launcher ----------------
extern "C" void kernel_launch(void* const* d_in, const int* in_sizes, int n_in,
                              void* d_out, int out_size, void* d_ws, size_t ws_size,
                              hipStream_t stream) {
  (void)in_sizes; (void)n_in; (void)out_size; (void)ws_size;
  const float* x      = (const float*)d_in[0];
  const float* qkv_w  = (const float*)d_in[1];
  const float* qkv_b  = (const float*)d_in[2];
  const float* proj_w = (const float*)d_in[3];
  const float* proj_b = (const float*)d_in[4];
  const float* ppw    = (const float*)d_in[5];
  const float* ppb    = (const float*)d_in[6];
  const float* ln1_g  = (const float*)d_in[7];
  const float* ln1_b  = (const float*)d_in[8];
  const float* w1     = (const float*)d_in[9];
  const float* b1     = (const float*)d_in[10];
  const float* ln2_g  = (const float*)d_in[11];
  const float* ln2_b  = (const float*)d_in[12];
  const float* w2     = (const float*)d_in[13];
  const float* b2     = (const float*)d_in[14];
  const float* ln3_g  = (const float*)d_in[15];
  const float* ln3_b  = (const float*)d_in[16];
  const float* w3     = (const float*)d_in[17];
  const float* b3     = (const float*)d_in[18];
  const float* biases = (const float*)d_in[19];
  const int*   relidx = (const int*)d_in[20];

  char* ws = (char*)d_ws;
  bf16*  wT   = (bf16*)(ws + WS_WT);
  bf16*  pjT  = (bf16*)(ws + WS_PJT);
  float* p_ws = (float*)(ws + WS_P);
  float* rpbQ = (float*)(ws + WS_RPBQ);

  prep_weights<<<1024, 256, 0, stream>>>(qkv_w, proj_w, wT, pjT);
  pos_mlp<<<1, 256, 0, stream>>>(biases, ppw, ppb,
                                 ln1_g, ln1_b, w1, b1,
                                 ln2_g, ln2_b, w2, b2,
                                 ln3_g, ln3_b, w3, b3, p_ws);
  build_rpbQ<<<128, 256, 0, stream>>>(p_ws, relidx, rpbQ);
  attn_fused<<<4096, 256, 0, stream>>>(x, wT, qkv_b, pjT, proj_b, rpbQ, (float*)d_out);
}

// Round 19
// 380.519 us; speedup vs baseline: 1.0533x; 1.0054x over previous
//
#include <hip/hip_runtime.h>
#include <cstddef>
#include <cstdint>

typedef __bf16 bf16;
typedef __bf16 bf16x8 __attribute__((ext_vector_type(8)));
typedef __bf16 bf16x4 __attribute__((ext_vector_type(4)));
typedef float  f32x4  __attribute__((ext_vector_type(4)));
typedef uint32_t u32x2 __attribute__((ext_vector_type(2)));
typedef uint32_t u32x4 __attribute__((ext_vector_type(4)));

#define NTOK 49
#define QK_SCALE 0.17677669529663687f   // 32^-0.5
#define LOG2E    1.4426950408889634f
#define QS       (QK_SCALE * LOG2E)     // folded into wT q-cols (prep) + q bias
#define LROW 528                        // LDS row stride bytes (264 bf16): 132 dw == 4 mod 32
                                        // -> row r shifts banks by 4r; defeats the 512B
                                        // power-of-2 stride that made row invisible to banks

// workspace byte offsets
#define WS_WT   0          // 768*256 bf16 = 393216 B
#define WS_PJT  393216     // 256*256 bf16 = 131072 B
#define WS_P    524288     // 169*8 f32 (padded to 8192)
#define WS_RPBQ 532480     // 8*64*64 f32 = 131072 B (end: 663552)

// ---------------- prep: transpose + bf16-convert weights ----------------
__global__ void prep_weights(const float* __restrict__ qkv_w, const float* __restrict__ proj_w,
                             bf16* __restrict__ wT, bf16* __restrict__ pjT) {
  int tid = blockIdx.x * 256 + threadIdx.x;
  if (tid < 768 * 256) {
    int n = tid >> 8, k = tid & 255;
    float v = qkv_w[k * 768 + n];
    if (n < 256) v *= QS;
    wT[tid] = (bf16)v;                          // wT[n][k]
  } else {
    int t = tid - 768 * 256;
    int n = t >> 8, k = t & 255;
    pjT[t] = (bf16)proj_w[k * 256 + n];         // pjT[n][k]
  }
}

// ---------------- prep: position-bias MLP (169 rows, tiny) ----------------
__device__ __forceinline__ void mlp_layer(float* p, const float* g, const float* be,
                                          const float* w, const float* bb, int nout) {
  float m = 0.f;
#pragma unroll
  for (int j = 0; j < 16; ++j) m += p[j];
  m *= (1.f / 16.f);
  float v = 0.f;
#pragma unroll
  for (int j = 0; j < 16; ++j) { float d = p[j] - m; v += d * d; }
  v *= (1.f / 16.f);
  float rs = rsqrtf(v + 1e-5f);
  float t[16];
#pragma unroll
  for (int j = 0; j < 16; ++j) {
    float u = (p[j] - m) * rs * g[j] + be[j];
    t[j] = u > 0.f ? u : 0.f;
  }
  float o[16];
  for (int j = 0; j < nout; ++j) {
    float s = bb[j];
#pragma unroll
    for (int k = 0; k < 16; ++k) s += t[k] * w[k * nout + j];
    o[j] = s;
  }
  for (int j = 0; j < nout; ++j) p[j] = o[j];
}

__global__ void pos_mlp(const float* __restrict__ biases, const float* __restrict__ ppw,
                        const float* __restrict__ ppb,
                        const float* g1, const float* be1, const float* w1, const float* bb1,
                        const float* g2, const float* be2, const float* w2, const float* bb2,
                        const float* g3, const float* be3, const float* w3, const float* bb3,
                        float* __restrict__ p_out) {
  int i = blockIdx.x * blockDim.x + threadIdx.x;
  if (i >= 169) return;
  float p[16];
  float y0 = biases[2 * i], y1 = biases[2 * i + 1];
#pragma unroll
  for (int j = 0; j < 16; ++j) p[j] = y0 * ppw[j] + y1 * ppw[16 + j] + ppb[j];
  mlp_layer(p, g1, be1, w1, bb1, 16);
  mlp_layer(p, g2, be2, w2, bb2, 16);
  mlp_layer(p, g3, be3, w3, bb3, 8);
#pragma unroll
  for (int j = 0; j < 8; ++j) p_out[i * 8 + j] = p[j];
}

// rpbQ[h][qt][kt], 8 x 64 x 64, pre-scaled by LOG2E, key-mask baked in.
// (qt-major so S^T C-init reads f32x4 contiguous in kt)
__global__ void build_rpbQ(const float* __restrict__ p, const int* __restrict__ rel_idx,
                           float* __restrict__ rpbQ) {
  int tid = blockIdx.x * 256 + threadIdx.x;
  if (tid >= 8 * 64 * 64) return;
  int h = tid >> 12, qt = (tid >> 6) & 63, kt = tid & 63;
  float v;
  if (kt >= NTOK) v = -1e30f;                      // padded key -> exp2 -> 0
  else if (qt >= NTOK) v = 0.f;                    // padded query row -> harmless
  else v = p[rel_idx[qt * NTOK + kt] * 8 + h] * LOG2E;
  rpbQ[tid] = v;
}

// ---------------- helpers ----------------
__device__ __forceinline__ u32x2 pack4(f32x4 a) {
  uint32_t h0 = (uint32_t)__builtin_bit_cast(uint16_t, (bf16)a[0]);
  uint32_t h1 = (uint32_t)__builtin_bit_cast(uint16_t, (bf16)a[1]);
  uint32_t h2 = (uint32_t)__builtin_bit_cast(uint16_t, (bf16)a[2]);
  uint32_t h3 = (uint32_t)__builtin_bit_cast(uint16_t, (bf16)a[3]);
  u32x2 r;
  r[0] = h0 | (h1 << 16);
  r[1] = h2 | (h3 << 16);
  return r;
}

// C-layout 32x16 tile pair (pk0: rows 0-15, pk1: rows 16-31; each u32x2 =
// bf16x4 over r2) -> A/B-frag of C^T: frag[lane][j] = C[8*(lane>>4)+j][lane&15].
__device__ __forceinline__ bf16x8 xpose_frag(u32x2 pk0, u32x2 pk1, int lg, int lr) {
  const int sl0 = ((lg & 1) << 5) + lr;
  const int sl1 = sl0 + 16;
  const bool hi = lg >= 2;
  uint32_t a0 = (uint32_t)__shfl((int)pk0[0], sl0, 64);
  uint32_t b0 = (uint32_t)__shfl((int)pk1[0], sl0, 64);
  uint32_t a1 = (uint32_t)__shfl((int)pk0[1], sl0, 64);
  uint32_t b1 = (uint32_t)__shfl((int)pk1[1], sl0, 64);
  uint32_t a2 = (uint32_t)__shfl((int)pk0[0], sl1, 64);
  uint32_t b2 = (uint32_t)__shfl((int)pk1[0], sl1, 64);
  uint32_t a3 = (uint32_t)__shfl((int)pk0[1], sl1, 64);
  uint32_t b3 = (uint32_t)__shfl((int)pk1[1], sl1, 64);
  u32x4 r;
  r[0] = hi ? b0 : a0; r[1] = hi ? b1 : a1;
  r[2] = hi ? b2 : a2; r[3] = hi ? b3 : a3;
  return __builtin_bit_cast(bf16x8, r);
}

// ---------------- fused per-window attention ----------------
// block = 256 threads (4 waves) = 1 window. Wave w owns heads {w, 4+w}.
// R19 = R14 (381us best: (256,2) cap, split q/k passes, acc peak 32,
// unroll-2, per-nq fused softmax/PV, direct ao_lds PV writes) with ONE
// change: LDS row stride 512 -> 528 B (264 bf16) and NO XOR swizzle.
// Rationale: 512B = 0 mod the 128B bank wrap, so row number never reached
// the bank bits - the frag reads' 8-lane groups (4 lg x 2 lr-halves with
// equal lg^(lr&7)) were ~8-way bank conflicts (SQ_LDS_BANK_CONFLICT 2.5e7
// ~ 10% of cycles). 528/4 = 132 == 4 mod 32 -> row r shifts banks by 4r;
// the conflicting rows differ mod 8 -> distinct shifts -> <=2-way (free).
// LDS 2 x 33792 = 67.6 KB -> still 2 blocks/CU. Also deletes the XOR ALU.
__launch_bounds__(256, 2)
__global__ void attn_fused(const float* __restrict__ x, const bf16* __restrict__ wT,
                           const float* __restrict__ qkv_b, const bf16* __restrict__ pjT,
                           const float* __restrict__ proj_b, const float* __restrict__ rpbQ,
                           float* __restrict__ out) {
  __shared__ __align__(16) bf16 x_lds[64 * 264];   // padded stride, no swizzle
  __shared__ __align__(16) bf16 ao_lds[64 * 264];  // attn-out tile, same stride

  const int b = blockIdx.x;
  const int tid = threadIdx.x;
  const int w = tid >> 6;
  const int lane = tid & 63;
  const int lg = lane >> 4;
  const int lr = lane & 15;

  char* const xbase = (char*)x_lds;
  char* const abase = (char*)ao_lds;

  // ---- stage x -> bf16 LDS, rows >= 49 zeroed (pad bytes never read) ----
  const float* xb = x + (size_t)b * (NTOK * 256);
#pragma unroll
  for (int it = 0; it < 16; ++it) {
    int r = it * 4 + w;
    float4 v = make_float4(0.f, 0.f, 0.f, 0.f);
    if (r < NTOK) v = *(const float4*)(xb + r * 256 + 4 * lane);
    bf16x4 pk;
    pk[0] = (bf16)v.x; pk[1] = (bf16)v.y; pk[2] = (bf16)v.z; pk[3] = (bf16)v.w;
    *(bf16x4*)(xbase + r * LROW + 8 * lane) = pk;
  }
  __syncthreads();

  const f32x4 zero4 = {0.f, 0.f, 0.f, 0.f};

#pragma unroll
  for (int hi = 0; hi < 2; ++hi) {
    const int h = hi * 4 + w;

    const bf16* wq0 = wT + (size_t)(h * 32 + lr) * 256 + 8 * lg;
    const bf16* wq1 = wq0 + 16 * 256;
    const bf16* wk0 = wq0 + 256 * 256;
    const bf16* wk1 = wk0 + 16 * 256;
    const bf16* wv0 = wk0 + 256 * 256;
    const bf16* wv1 = wv0 + 16 * 256;

    f32x4 acc_[2][4];   // reused by q-pass then k-pass (acc peak 32)
    bf16x8 aqf[4], bkf[4];

    // ---- q pass: qT GEMM over K=256 (C rows = dims, cols = tokens) ----
#pragma unroll
    for (int mt = 0; mt < 2; ++mt)
#pragma unroll
      for (int nt = 0; nt < 4; ++nt) acc_[mt][nt] = zero4;
#pragma unroll 2
    for (int kk = 0; kk < 8; ++kk) {
      bf16x8 xf[4];
#pragma unroll
      for (int nt = 0; nt < 4; ++nt)
        xf[nt] = *(const bf16x8*)(xbase + (nt * 16 + lr) * LROW + 64 * kk + 16 * lg);
      bf16x8 q0f = *(const bf16x8*)&wq0[kk * 32];
      bf16x8 q1f = *(const bf16x8*)&wq1[kk * 32];
#pragma unroll
      for (int nt = 0; nt < 4; ++nt) {
        acc_[0][nt] = __builtin_amdgcn_mfma_f32_16x16x32_bf16(q0f, xf[nt], acc_[0][nt], 0, 0, 0);
        acc_[1][nt] = __builtin_amdgcn_mfma_f32_16x16x32_bf16(q1f, xf[nt], acc_[1][nt], 0, 0, 0);
      }
    }
    {
      f32x4 qb0 = *(const f32x4*)&qkv_b[h * 32 + 4 * lg];
      f32x4 qb1 = *(const f32x4*)&qkv_b[h * 32 + 16 + 4 * lg];
#pragma unroll
      for (int t = 0; t < 4; ++t) {
        f32x4 tq0, tq1;
#pragma unroll
        for (int r2 = 0; r2 < 4; ++r2) {
          tq0[r2] = acc_[0][t][r2] + qb0[r2] * QS;
          tq1[r2] = acc_[1][t][r2] + qb1[r2] * QS;
        }
        aqf[t] = xpose_frag(pack4(tq0), pack4(tq1), lg, lr);
      }
    }

    // ---- k pass: kT GEMM (same acc array) ----
#pragma unroll
    for (int mt = 0; mt < 2; ++mt)
#pragma unroll
      for (int nt = 0; nt < 4; ++nt) acc_[mt][nt] = zero4;
#pragma unroll 2
    for (int kk = 0; kk < 8; ++kk) {
      bf16x8 xf[4];
#pragma unroll
      for (int nt = 0; nt < 4; ++nt)
        xf[nt] = *(const bf16x8*)(xbase + (nt * 16 + lr) * LROW + 64 * kk + 16 * lg);
      bf16x8 k0f = *(const bf16x8*)&wk0[kk * 32];
      bf16x8 k1f = *(const bf16x8*)&wk1[kk * 32];
#pragma unroll
      for (int nt = 0; nt < 4; ++nt) {
        acc_[0][nt] = __builtin_amdgcn_mfma_f32_16x16x32_bf16(k0f, xf[nt], acc_[0][nt], 0, 0, 0);
        acc_[1][nt] = __builtin_amdgcn_mfma_f32_16x16x32_bf16(k1f, xf[nt], acc_[1][nt], 0, 0, 0);
      }
    }
    {
      f32x4 kb0 = *(const f32x4*)&qkv_b[256 + h * 32 + 4 * lg];
      f32x4 kb1 = *(const f32x4*)&qkv_b[256 + h * 32 + 16 + 4 * lg];
#pragma unroll
      for (int t = 0; t < 4; ++t) {
        f32x4 tk0, tk1;
#pragma unroll
        for (int r2 = 0; r2 < 4; ++r2) {
          tk0[r2] = acc_[0][t][r2] + kb0[r2];
          tk1[r2] = acc_[1][t][r2] + kb1[r2];
        }
        bkf[t] = xpose_frag(pack4(tk0), pack4(tk1), lg, lr);
      }
    }

    // ---- v pass: v GEMM (C rows = tokens, cols = vdims) ----
    f32x4 av_[4][2];
#pragma unroll
    for (int m = 0; m < 4; ++m) { av_[m][0] = zero4; av_[m][1] = zero4; }
#pragma unroll 2
    for (int kk = 0; kk < 8; ++kk) {
      bf16x8 xf[4];
#pragma unroll
      for (int m = 0; m < 4; ++m)
        xf[m] = *(const bf16x8*)(xbase + (m * 16 + lr) * LROW + 64 * kk + 16 * lg);
      bf16x8 v0f = *(const bf16x8*)&wv0[kk * 32];
      bf16x8 v1f = *(const bf16x8*)&wv1[kk * 32];
#pragma unroll
      for (int m = 0; m < 4; ++m) {
        av_[m][0] = __builtin_amdgcn_mfma_f32_16x16x32_bf16(xf[m], v0f, av_[m][0], 0, 0, 0);
        av_[m][1] = __builtin_amdgcn_mfma_f32_16x16x32_bf16(xf[m], v1f, av_[m][1], 0, 0, 0);
      }
    }
    // v bias (cols = vdims -> uniform over r2), pack, transpose
    bf16x8 vf0[2], vf1[2];
    {
      const float vbA = qkv_b[512 + h * 32 + lr];
      const float vbB = qkv_b[512 + h * 32 + 16 + lr];
#pragma unroll
      for (int nv = 0; nv < 2; ++nv) {
        const float vb = nv ? vbB : vbA;
        f32x4 t0, t1, t2, t3;
#pragma unroll
        for (int r2 = 0; r2 < 4; ++r2) {
          t0[r2] = av_[0][nv][r2] + vb;
          t1[r2] = av_[1][nv][r2] + vb;
          t2[r2] = av_[2][nv][r2] + vb;
          t3[r2] = av_[3][nv][r2] + vb;
        }
        vf0[nv] = xpose_frag(pack4(t0), pack4(t1), lg, lr);
        vf1[nv] = xpose_frag(pack4(t2), pack4(t3), lg, lr);
      }
    }

    // ---- per-nq: QK^T column -> softmax -> PV -> direct ao_lds write ----
    // Sc[mk] C element (lane,r2) = S^T[key = mk*16+4lg+r2][q = nq*16+lr]
    const float* rpbh = rpbQ + h * 4096;
#pragma unroll
    for (int nq = 0; nq < 4; ++nq) {
      f32x4 Sc[4];
#pragma unroll
      for (int mk = 0; mk < 4; ++mk) {
        f32x4 rv = *(const f32x4*)&rpbh[(nq * 16 + lr) * 64 + mk * 16 + 4 * lg];
        Sc[mk] = __builtin_amdgcn_mfma_f32_16x16x32_bf16(bkf[mk], aqf[nq], rv, 0, 0, 0);
      }
      // softmax (base-2) over this q-column: 16 in-reg + shfl over lg axis
      float mx = -3.0e38f;
#pragma unroll
      for (int mk = 0; mk < 4; ++mk)
#pragma unroll
        for (int r2 = 0; r2 < 4; ++r2) mx = fmaxf(mx, Sc[mk][r2]);
      mx = fmaxf(mx, __shfl_xor(mx, 16, 64));
      mx = fmaxf(mx, __shfl_xor(mx, 32, 64));
      float sum = 0.f;
#pragma unroll
      for (int mk = 0; mk < 4; ++mk)
#pragma unroll
        for (int r2 = 0; r2 < 4; ++r2) {
          float e = exp2f(Sc[mk][r2] - mx);
          Sc[mk][r2] = e;
          sum += e;
        }
      sum += __shfl_xor(sum, 16, 64);
      sum += __shfl_xor(sum, 32, 64);
      const float inv = 1.f / sum;
#pragma unroll
      for (int mk = 0; mk < 4; ++mk)
#pragma unroll
        for (int r2 = 0; r2 < 4; ++r2) Sc[mk][r2] *= inv;

      // pack + transpose -> PV A-frags for this q-row block (local, 8 regs)
      bf16x8 pa0 = xpose_frag(pack4(Sc[0]), pack4(Sc[1]), lg, lr);  // keys 0-31
      bf16x8 pa1 = xpose_frag(pack4(Sc[2]), pack4(Sc[3]), lg, lr);  // keys 32-63

      // PV for rows nq*16..+15: o = P @ V, write straight to ao_lds
#pragma unroll
      for (int nv = 0; nv < 2; ++nv) {
        f32x4 o = __builtin_amdgcn_mfma_f32_16x16x32_bf16(pa0, vf0[nv], zero4, 0, 0, 0);
        o = __builtin_amdgcn_mfma_f32_16x16x32_bf16(pa1, vf1[nv], o, 0, 0, 0);
        bf16x4 pk = __builtin_bit_cast(bf16x4, pack4(o));
#pragma unroll
        for (int r2 = 0; r2 < 4; ++r2) {
          const int r = nq * 16 + 4 * lg + r2;
          *(bf16*)(abase + r * LROW + 2 * (h * 32 + nv * 16 + lr)) = pk[r2];
        }
      }
    }
  }

  __syncthreads();  // all ao writes visible

  // ---- proj: out = ao(64x256) @ proj_w + b; wave w owns 64 output cols ----
  f32x4 c2[4][4];
  const bf16* pjrow[4];
#pragma unroll
  for (int n = 0; n < 4; ++n) {
    const int col = w * 64 + n * 16 + lr;
    const float pb = proj_b[col];
#pragma unroll
    for (int m = 0; m < 4; ++m) {
      c2[m][n][0] = pb; c2[m][n][1] = pb; c2[m][n][2] = pb; c2[m][n][3] = pb;
    }
    pjrow[n] = pjT + (size_t)col * 256 + 8 * lg;
  }
#pragma unroll 2
  for (int kk = 0; kk < 8; ++kk) {
    bf16x8 afr[4];
#pragma unroll
    for (int m = 0; m < 4; ++m)
      afr[m] = *(const bf16x8*)(abase + (m * 16 + lr) * LROW + 64 * kk + 16 * lg);
#pragma unroll
    for (int n = 0; n < 4; ++n) {
      bf16x8 bfr = *(const bf16x8*)&pjrow[n][kk * 32];
#pragma unroll
      for (int m = 0; m < 4; ++m)
        c2[m][n] = __builtin_amdgcn_mfma_f32_16x16x32_bf16(afr[m], bfr, c2[m][n], 0, 0, 0);
    }
  }
  float* ob = out + (size_t)b * (NTOK * 256);
#pragma unroll
  for (int n = 0; n < 4; ++n) {
    const int col = w * 64 + n * 16 + lr;
#pragma unroll
    for (int m = 0; m < 4; ++m)
#pragma unroll
      for (int r2 = 0; r2 < 4; ++r2) {
        const int row = m * 16 + lg * 4 + r2;
        if (row < NTOK) ob[row * 256 + col] = c2[m][n][r2];
      }
  }
}

// ---------------- launcher ----------------
extern "C" void kernel_launch(void* const* d_in, const int* in_sizes, int n_in,
                              void* d_out, int out_size, void* d_ws, size_t ws_size,
                              hipStream_t stream) {
  (void)in_sizes; (void)n_in; (void)out_size; (void)ws_size;
  const float* x      = (const float*)d_in[0];
  const float* qkv_w  = (const float*)d_in[1];
  const float* qkv_b  = (const float*)d_in[2];
  const float* proj_w = (const float*)d_in[3];
  const float* proj_b = (const float*)d_in[4];
  const float* ppw    = (const float*)d_in[5];
  const float* ppb    = (const float*)d_in[6];
  const float* ln1_g  = (const float*)d_in[7];
  const float* ln1_b  = (const float*)d_in[8];
  const float* w1     = (const float*)d_in[9];
  const float* b1     = (const float*)d_in[10];
  const float* ln2_g  = (const float*)d_in[11];
  const float* ln2_b  = (const float*)d_in[12];
  const float* w2     = (const float*)d_in[13];
  const float* b2     = (const float*)d_in[14];
  const float* ln3_g  = (const float*)d_in[15];
  const float* ln3_b  = (const float*)d_in[16];
  const float* w3     = (const float*)d_in[17];
  const float* b3     = (const float*)d_in[18];
  const float* biases = (const float*)d_in[19];
  const int*   relidx = (const int*)d_in[20];

  char* ws = (char*)d_ws;
  bf16*  wT   = (bf16*)(ws + WS_WT);
  bf16*  pjT  = (bf16*)(ws + WS_PJT);
  float* p_ws = (float*)(ws + WS_P);
  float* rpbQ = (float*)(ws + WS_RPBQ);

  prep_weights<<<1024, 256, 0, stream>>>(qkv_w, proj_w, wT, pjT);
  pos_mlp<<<1, 256, 0, stream>>>(biases, ppw, ppb,
                                 ln1_g, ln1_b, w1, b1,
                                 ln2_g, ln2_b, w2, b2,
                                 ln3_g, ln3_b, w3, b3, p_ws);
  build_rpbQ<<<128, 256, 0, stream>>>(p_ws, relidx, rpbQ);
  attn_fused<<<4096, 256, 0, stream>>>(x, wT, qkv_b, pjT, proj_b, rpbQ, (float*)d_out);
}

// Round 20
// 377.009 us; speedup vs baseline: 1.0631x; 1.0093x over previous
//
#include <hip/hip_runtime.h>
#include <cstddef>
#include <cstdint>

typedef __bf16 bf16;
typedef __bf16 bf16x8 __attribute__((ext_vector_type(8)));
typedef __bf16 bf16x4 __attribute__((ext_vector_type(4)));
typedef float  f32x4  __attribute__((ext_vector_type(4)));
typedef uint32_t u32x2 __attribute__((ext_vector_type(2)));
typedef uint32_t u32x4 __attribute__((ext_vector_type(4)));

#define NTOK 49
#define QK_SCALE 0.17677669529663687f   // 32^-0.5
#define LOG2E    1.4426950408889634f
#define QS       (QK_SCALE * LOG2E)     // folded into wT q-cols (prep) + q bias
#define LROW 528                        // LDS row stride bytes (264 bf16), no swizzle

// workspace byte offsets
#define WS_WT   0          // 768*256 bf16 = 393216 B
#define WS_PJT  393216     // 256*256 bf16 = 131072 B
#define WS_P    524288     // 169*8 f32 (padded to 8192)
#define WS_RPBQ 532480     // 8*64*64 f32 = 131072 B (end: 663552)

// ---------------- prep: transpose + bf16-convert weights ----------------
__global__ void prep_weights(const float* __restrict__ qkv_w, const float* __restrict__ proj_w,
                             bf16* __restrict__ wT, bf16* __restrict__ pjT) {
  int tid = blockIdx.x * 256 + threadIdx.x;
  if (tid < 768 * 256) {
    int n = tid >> 8, k = tid & 255;
    float v = qkv_w[k * 768 + n];
    if (n < 256) v *= QS;
    wT[tid] = (bf16)v;                          // wT[n][k]
  } else {
    int t = tid - 768 * 256;
    int n = t >> 8, k = t & 255;
    pjT[t] = (bf16)proj_w[k * 256 + n];         // pjT[n][k]
  }
}

// ---------------- prep: position-bias MLP (169 rows, tiny) ----------------
__device__ __forceinline__ void mlp_layer(float* p, const float* g, const float* be,
                                          const float* w, const float* bb, int nout) {
  float m = 0.f;
#pragma unroll
  for (int j = 0; j < 16; ++j) m += p[j];
  m *= (1.f / 16.f);
  float v = 0.f;
#pragma unroll
  for (int j = 0; j < 16; ++j) { float d = p[j] - m; v += d * d; }
  v *= (1.f / 16.f);
  float rs = rsqrtf(v + 1e-5f);
  float t[16];
#pragma unroll
  for (int j = 0; j < 16; ++j) {
    float u = (p[j] - m) * rs * g[j] + be[j];
    t[j] = u > 0.f ? u : 0.f;
  }
  float o[16];
  for (int j = 0; j < nout; ++j) {
    float s = bb[j];
#pragma unroll
    for (int k = 0; k < 16; ++k) s += t[k] * w[k * nout + j];
    o[j] = s;
  }
  for (int j = 0; j < nout; ++j) p[j] = o[j];
}

__global__ void pos_mlp(const float* __restrict__ biases, const float* __restrict__ ppw,
                        const float* __restrict__ ppb,
                        const float* g1, const float* be1, const float* w1, const float* bb1,
                        const float* g2, const float* be2, const float* w2, const float* bb2,
                        const float* g3, const float* be3, const float* w3, const float* bb3,
                        float* __restrict__ p_out) {
  int i = blockIdx.x * blockDim.x + threadIdx.x;
  if (i >= 169) return;
  float p[16];
  float y0 = biases[2 * i], y1 = biases[2 * i + 1];
#pragma unroll
  for (int j = 0; j < 16; ++j) p[j] = y0 * ppw[j] + y1 * ppw[16 + j] + ppb[j];
  mlp_layer(p, g1, be1, w1, bb1, 16);
  mlp_layer(p, g2, be2, w2, bb2, 16);
  mlp_layer(p, g3, be3, w3, bb3, 8);
#pragma unroll
  for (int j = 0; j < 8; ++j) p_out[i * 8 + j] = p[j];
}

// rpbQ[h][qt][kt], 8 x 64 x 64, pre-scaled by LOG2E, key-mask baked in.
__global__ void build_rpbQ(const float* __restrict__ p, const int* __restrict__ rel_idx,
                           float* __restrict__ rpbQ) {
  int tid = blockIdx.x * 256 + threadIdx.x;
  if (tid >= 8 * 64 * 64) return;
  int h = tid >> 12, qt = (tid >> 6) & 63, kt = tid & 63;
  float v;
  if (kt >= NTOK) v = -1e30f;                      // padded key -> exp2 -> 0
  else if (qt >= NTOK) v = 0.f;                    // padded query row -> harmless
  else v = p[rel_idx[qt * NTOK + kt] * 8 + h] * LOG2E;
  rpbQ[tid] = v;
}

// ---------------- helpers ----------------
__device__ __forceinline__ u32x2 pack4(f32x4 a) {
  uint32_t h0 = (uint32_t)__builtin_bit_cast(uint16_t, (bf16)a[0]);
  uint32_t h1 = (uint32_t)__builtin_bit_cast(uint16_t, (bf16)a[1]);
  uint32_t h2 = (uint32_t)__builtin_bit_cast(uint16_t, (bf16)a[2]);
  uint32_t h3 = (uint32_t)__builtin_bit_cast(uint16_t, (bf16)a[3]);
  u32x2 r;
  r[0] = h0 | (h1 << 16);
  r[1] = h2 | (h3 << 16);
  return r;
}

// C-layout 32x16 tile pair -> A/B-frag of C^T: frag[lane][j] = C[8*(lane>>4)+j][lane&15].
__device__ __forceinline__ bf16x8 xpose_frag(u32x2 pk0, u32x2 pk1, int lg, int lr) {
  const int sl0 = ((lg & 1) << 5) + lr;
  const int sl1 = sl0 + 16;
  const bool hi = lg >= 2;
  uint32_t a0 = (uint32_t)__shfl((int)pk0[0], sl0, 64);
  uint32_t b0 = (uint32_t)__shfl((int)pk1[0], sl0, 64);
  uint32_t a1 = (uint32_t)__shfl((int)pk0[1], sl0, 64);
  uint32_t b1 = (uint32_t)__shfl((int)pk1[1], sl0, 64);
  uint32_t a2 = (uint32_t)__shfl((int)pk0[0], sl1, 64);
  uint32_t b2 = (uint32_t)__shfl((int)pk1[0], sl1, 64);
  uint32_t a3 = (uint32_t)__shfl((int)pk0[1], sl1, 64);
  uint32_t b3 = (uint32_t)__shfl((int)pk1[1], sl1, 64);
  u32x4 r;
  r[0] = hi ? b0 : a0; r[1] = hi ? b1 : a1;
  r[2] = hi ? b2 : a2; r[3] = hi ? b3 : a3;
  return __builtin_bit_cast(bf16x8, r);
}

// ---------------- fused per-window attention ----------------
// block = 256 threads (4 waves) = 1 window. Wave w owns heads {w, 4+w}.
// R20 = R19 (380.5us: (256,2) cap, pad-528 no-swizzle LDS, acc-lean tail,
// per-nq fused softmax/PV, direct ao_lds PV writes) with ONE change:
// q+k GEMM re-fused into a single kk loop. Factorial algebra over
// R15/R16/R18 isolates: proj-swap ~ +10us, pairing ~ +1us, so fusion alone
// ~ -2us (the only untested isolate with a negative point estimate).
// Deletes 32 of 96 ds_read_b128 per head-wave (GEMM1 LDS reads -33%);
// acc peak 64 <= 128 AGPR; arch ~100 <= 128 cap (WRITE_SIZE is the tell).
__launch_bounds__(256, 2)
__global__ void attn_fused(const float* __restrict__ x, const bf16* __restrict__ wT,
                           const float* __restrict__ qkv_b, const bf16* __restrict__ pjT,
                           const float* __restrict__ proj_b, const float* __restrict__ rpbQ,
                           float* __restrict__ out) {
  __shared__ __align__(16) bf16 x_lds[64 * 264];   // padded stride, no swizzle
  __shared__ __align__(16) bf16 ao_lds[64 * 264];  // attn-out tile, same stride

  const int b = blockIdx.x;
  const int tid = threadIdx.x;
  const int w = tid >> 6;
  const int lane = tid & 63;
  const int lg = lane >> 4;
  const int lr = lane & 15;

  char* const xbase = (char*)x_lds;
  char* const abase = (char*)ao_lds;

  // ---- stage x -> bf16 LDS, rows >= 49 zeroed ----
  const float* xb = x + (size_t)b * (NTOK * 256);
#pragma unroll
  for (int it = 0; it < 16; ++it) {
    int r = it * 4 + w;
    float4 v = make_float4(0.f, 0.f, 0.f, 0.f);
    if (r < NTOK) v = *(const float4*)(xb + r * 256 + 4 * lane);
    bf16x4 pk;
    pk[0] = (bf16)v.x; pk[1] = (bf16)v.y; pk[2] = (bf16)v.z; pk[3] = (bf16)v.w;
    *(bf16x4*)(xbase + r * LROW + 8 * lane) = pk;
  }
  __syncthreads();

  const f32x4 zero4 = {0.f, 0.f, 0.f, 0.f};

#pragma unroll
  for (int hi = 0; hi < 2; ++hi) {
    const int h = hi * 4 + w;

    const bf16* wq0 = wT + (size_t)(h * 32 + lr) * 256 + 8 * lg;
    const bf16* wq1 = wq0 + 16 * 256;
    const bf16* wk0 = wq0 + 256 * 256;
    const bf16* wk1 = wk0 + 16 * 256;
    const bf16* wv0 = wk0 + 256 * 256;
    const bf16* wv1 = wv0 + 16 * 256;

    // ---- fused qT+kT GEMM over K=256 (C rows = dims, cols = tokens) ----
    f32x4 aq_[2][4], ak_[2][4];          // 64 acc regs (AGPR side, <=128)
    bf16x8 aqf[4], bkf[4];
#pragma unroll
    for (int mt = 0; mt < 2; ++mt)
#pragma unroll
      for (int nt = 0; nt < 4; ++nt) { aq_[mt][nt] = zero4; ak_[mt][nt] = zero4; }
#pragma unroll 2
    for (int kk = 0; kk < 8; ++kk) {
      bf16x8 xf[4];
#pragma unroll
      for (int nt = 0; nt < 4; ++nt)
        xf[nt] = *(const bf16x8*)(xbase + (nt * 16 + lr) * LROW + 64 * kk + 16 * lg);
      bf16x8 q0f = *(const bf16x8*)&wq0[kk * 32];
      bf16x8 q1f = *(const bf16x8*)&wq1[kk * 32];
      bf16x8 k0f = *(const bf16x8*)&wk0[kk * 32];
      bf16x8 k1f = *(const bf16x8*)&wk1[kk * 32];
#pragma unroll
      for (int nt = 0; nt < 4; ++nt) {
        aq_[0][nt] = __builtin_amdgcn_mfma_f32_16x16x32_bf16(q0f, xf[nt], aq_[0][nt], 0, 0, 0);
        aq_[1][nt] = __builtin_amdgcn_mfma_f32_16x16x32_bf16(q1f, xf[nt], aq_[1][nt], 0, 0, 0);
        ak_[0][nt] = __builtin_amdgcn_mfma_f32_16x16x32_bf16(k0f, xf[nt], ak_[0][nt], 0, 0, 0);
        ak_[1][nt] = __builtin_amdgcn_mfma_f32_16x16x32_bf16(k1f, xf[nt], ak_[1][nt], 0, 0, 0);
      }
    }
    // q/k bias (rows = dims -> varies with r2), pack, transpose
    {
      f32x4 qb0 = *(const f32x4*)&qkv_b[h * 32 + 4 * lg];
      f32x4 qb1 = *(const f32x4*)&qkv_b[h * 32 + 16 + 4 * lg];
      f32x4 kb0 = *(const f32x4*)&qkv_b[256 + h * 32 + 4 * lg];
      f32x4 kb1 = *(const f32x4*)&qkv_b[256 + h * 32 + 16 + 4 * lg];
#pragma unroll
      for (int t = 0; t < 4; ++t) {
        f32x4 tq0, tq1, tk0, tk1;
#pragma unroll
        for (int r2 = 0; r2 < 4; ++r2) {
          tq0[r2] = aq_[0][t][r2] + qb0[r2] * QS;
          tq1[r2] = aq_[1][t][r2] + qb1[r2] * QS;
          tk0[r2] = ak_[0][t][r2] + kb0[r2];
          tk1[r2] = ak_[1][t][r2] + kb1[r2];
        }
        aqf[t] = xpose_frag(pack4(tq0), pack4(tq1), lg, lr);
        bkf[t] = xpose_frag(pack4(tk0), pack4(tk1), lg, lr);
      }
    }

    // ---- v pass: v GEMM (C rows = tokens, cols = vdims) ----
    f32x4 av_[4][2];
#pragma unroll
    for (int m = 0; m < 4; ++m) { av_[m][0] = zero4; av_[m][1] = zero4; }
#pragma unroll 2
    for (int kk = 0; kk < 8; ++kk) {
      bf16x8 xf[4];
#pragma unroll
      for (int m = 0; m < 4; ++m)
        xf[m] = *(const bf16x8*)(xbase + (m * 16 + lr) * LROW + 64 * kk + 16 * lg);
      bf16x8 v0f = *(const bf16x8*)&wv0[kk * 32];
      bf16x8 v1f = *(const bf16x8*)&wv1[kk * 32];
#pragma unroll
      for (int m = 0; m < 4; ++m) {
        av_[m][0] = __builtin_amdgcn_mfma_f32_16x16x32_bf16(xf[m], v0f, av_[m][0], 0, 0, 0);
        av_[m][1] = __builtin_amdgcn_mfma_f32_16x16x32_bf16(xf[m], v1f, av_[m][1], 0, 0, 0);
      }
    }
    // v bias (cols = vdims -> uniform over r2), pack, transpose
    bf16x8 vf0[2], vf1[2];
    {
      const float vbA = qkv_b[512 + h * 32 + lr];
      const float vbB = qkv_b[512 + h * 32 + 16 + lr];
#pragma unroll
      for (int nv = 0; nv < 2; ++nv) {
        const float vb = nv ? vbB : vbA;
        f32x4 t0, t1, t2, t3;
#pragma unroll
        for (int r2 = 0; r2 < 4; ++r2) {
          t0[r2] = av_[0][nv][r2] + vb;
          t1[r2] = av_[1][nv][r2] + vb;
          t2[r2] = av_[2][nv][r2] + vb;
          t3[r2] = av_[3][nv][r2] + vb;
        }
        vf0[nv] = xpose_frag(pack4(t0), pack4(t1), lg, lr);
        vf1[nv] = xpose_frag(pack4(t2), pack4(t3), lg, lr);
      }
    }

    // ---- per-nq: QK^T column -> softmax -> PV -> direct ao_lds write ----
    const float* rpbh = rpbQ + h * 4096;
#pragma unroll
    for (int nq = 0; nq < 4; ++nq) {
      f32x4 Sc[4];
#pragma unroll
      for (int mk = 0; mk < 4; ++mk) {
        f32x4 rv = *(const f32x4*)&rpbh[(nq * 16 + lr) * 64 + mk * 16 + 4 * lg];
        Sc[mk] = __builtin_amdgcn_mfma_f32_16x16x32_bf16(bkf[mk], aqf[nq], rv, 0, 0, 0);
      }
      // softmax (base-2) over this q-column: 16 in-reg + shfl over lg axis
      float mx = -3.0e38f;
#pragma unroll
      for (int mk = 0; mk < 4; ++mk)
#pragma unroll
        for (int r2 = 0; r2 < 4; ++r2) mx = fmaxf(mx, Sc[mk][r2]);
      mx = fmaxf(mx, __shfl_xor(mx, 16, 64));
      mx = fmaxf(mx, __shfl_xor(mx, 32, 64));
      float sum = 0.f;
#pragma unroll
      for (int mk = 0; mk < 4; ++mk)
#pragma unroll
        for (int r2 = 0; r2 < 4; ++r2) {
          float e = exp2f(Sc[mk][r2] - mx);
          Sc[mk][r2] = e;
          sum += e;
        }
      sum += __shfl_xor(sum, 16, 64);
      sum += __shfl_xor(sum, 32, 64);
      const float inv = 1.f / sum;
#pragma unroll
      for (int mk = 0; mk < 4; ++mk)
#pragma unroll
        for (int r2 = 0; r2 < 4; ++r2) Sc[mk][r2] *= inv;

      // pack + transpose -> PV A-frags (local, 8 regs)
      bf16x8 pa0 = xpose_frag(pack4(Sc[0]), pack4(Sc[1]), lg, lr);  // keys 0-31
      bf16x8 pa1 = xpose_frag(pack4(Sc[2]), pack4(Sc[3]), lg, lr);  // keys 32-63

      // PV for rows nq*16..+15: o = P @ V, write straight to ao_lds
#pragma unroll
      for (int nv = 0; nv < 2; ++nv) {
        f32x4 o = __builtin_amdgcn_mfma_f32_16x16x32_bf16(pa0, vf0[nv], zero4, 0, 0, 0);
        o = __builtin_amdgcn_mfma_f32_16x16x32_bf16(pa1, vf1[nv], o, 0, 0, 0);
        bf16x4 pk = __builtin_bit_cast(bf16x4, pack4(o));
#pragma unroll
        for (int r2 = 0; r2 < 4; ++r2) {
          const int r = nq * 16 + 4 * lg + r2;
          *(bf16*)(abase + r * LROW + 2 * (h * 32 + nv * 16 + lr)) = pk[r2];
        }
      }
    }
  }

  __syncthreads();  // all ao writes visible

  // ---- proj: out = ao(64x256) @ proj_w + b; wave w owns 64 output cols ----
  f32x4 c2[4][4];
  const bf16* pjrow[4];
#pragma unroll
  for (int n = 0; n < 4; ++n) {
    const int col = w * 64 + n * 16 + lr;
    const float pb = proj_b[col];
#pragma unroll
    for (int m = 0; m < 4; ++m) {
      c2[m][n][0] = pb; c2[m][n][1] = pb; c2[m][n][2] = pb; c2[m][n][3] = pb;
    }
    pjrow[n] = pjT + (size_t)col * 256 + 8 * lg;
  }
#pragma unroll 2
  for (int kk = 0; kk < 8; ++kk) {
    bf16x8 afr[4];
#pragma unroll
    for (int m = 0; m < 4; ++m)
      afr[m] = *(const bf16x8*)(abase + (m * 16 + lr) * LROW + 64 * kk + 16 * lg);
#pragma unroll
    for (int n = 0; n < 4; ++n) {
      bf16x8 bfr = *(const bf16x8*)&pjrow[n][kk * 32];
#pragma unroll
      for (int m = 0; m < 4; ++m)
        c2[m][n] = __builtin_amdgcn_mfma_f32_16x16x32_bf16(afr[m], bfr, c2[m][n], 0, 0, 0);
    }
  }
  float* ob = out + (size_t)b * (NTOK * 256);
#pragma unroll
  for (int n = 0; n < 4; ++n) {
    const int col = w * 64 + n * 16 + lr;
#pragma unroll
    for (int m = 0; m < 4; ++m)
#pragma unroll
      for (int r2 = 0; r2 < 4; ++r2) {
        const int row = m * 16 + lg * 4 + r2;
        if (row < NTOK) ob[row * 256 + col] = c2[m][n][r2];
      }
  }
}

// ---------------- launcher ----------------
extern "C" void kernel_launch(void* const* d_in, const int* in_sizes, int n_in,
                              void* d_out, int out_size, void* d_ws, size_t ws_size,
                              hipStream_t stream) {
  (void)in_sizes; (void)n_in; (void)out_size; (void)ws_size;
  const float* x      = (const float*)d_in[0];
  const float* qkv_w  = (const float*)d_in[1];
  const float* qkv_b  = (const float*)d_in[2];
  const float* proj_w = (const float*)d_in[3];
  const float* proj_b = (const float*)d_in[4];
  const float* ppw    = (const float*)d_in[5];
  const float* ppb    = (const float*)d_in[6];
  const float* ln1_g  = (const float*)d_in[7];
  const float* ln1_b  = (const float*)d_in[8];
  const float* w1     = (const float*)d_in[9];
  const float* b1     = (const float*)d_in[10];
  const float* ln2_g  = (const float*)d_in[11];
  const float* ln2_b  = (const float*)d_in[12];
  const float* w2     = (const float*)d_in[13];
  const float* b2     = (const float*)d_in[14];
  const float* ln3_g  = (const float*)d_in[15];
  const float* ln3_b  = (const float*)d_in[16];
  const float* w3     = (const float*)d_in[17];
  const float* b3     = (const float*)d_in[18];
  const float* biases = (const float*)d_in[19];
  const int*   relidx = (const int*)d_in[20];

  char* ws = (char*)d_ws;
  bf16*  wT   = (bf16*)(ws + WS_WT);
  bf16*  pjT  = (bf16*)(ws + WS_PJT);
  float* p_ws = (float*)(ws + WS_P);
  float* rpbQ = (float*)(ws + WS_RPBQ);

  prep_weights<<<1024, 256, 0, stream>>>(qkv_w, proj_w, wT, pjT);
  pos_mlp<<<1, 256, 0, stream>>>(biases, ppw, ppb,
                                 ln1_g, ln1_b, w1, b1,
                                 ln2_g, ln2_b, w2, b2,
                                 ln3_g, ln3_b, w3, b3, p_ws);
  build_rpbQ<<<128, 256, 0, stream>>>(p_ws, relidx, rpbQ);
  attn_fused<<<4096, 256, 0, stream>>>(x, wT, qkv_b, pjT, proj_b, rpbQ, (float*)d_out);
}